// Round 1
// baseline (219.045 us; speedup 1.0000x reference)
//
#include <hip/hip_runtime.h>

#define B_    64
#define HW_   196
#define HWP_  224
#define D_    768
#define E_    256
#define C_    10
#define MP_   (B_*HWP_)   // 14336 padded rows

typedef __bf16 bf16x8 __attribute__((ext_vector_type(8)));
typedef __bf16 bf16x4 __attribute__((ext_vector_type(4)));
typedef float  f32x4  __attribute__((ext_vector_type(4)));

// ---------------- K0x: fp32 x -> bf16 hi/lo, zero-padded [B][HWP][D] ----------------
__global__ __launch_bounds__(256) void k0_x(const float* __restrict__ x,
                                            __bf16* __restrict__ xhi,
                                            __bf16* __restrict__ xlo) {
  size_t i4 = ((size_t)blockIdx.x * 256 + threadIdx.x) * 4;   // grid sized exactly
  int d  = (int)(i4 % D_);
  size_t row = i4 / D_;
  int hp = (int)(row % HWP_);
  int b  = (int)(row / HWP_);
  float4 v = make_float4(0.f, 0.f, 0.f, 0.f);
  if (hp < HW_) v = *(const float4*)&x[((size_t)b * HW_ + hp) * D_ + d];
  float vv[4] = {v.x, v.y, v.z, v.w};
  bf16x4 h, l;
#pragma unroll
  for (int j = 0; j < 4; j++) {
    __bf16 hj = (__bf16)vv[j];
    float r = vv[j] - (float)hj;
    h[j] = hj;
    l[j] = (__bf16)r;
  }
  *(bf16x4*)&xhi[i4] = h;
  *(bf16x4*)&xlo[i4] = l;
}

// ---------------- K0w: fp32 ag_w -> bf16 hi/lo [E][D] ----------------
__global__ __launch_bounds__(256) void k0_w(const float* __restrict__ w,
                                            __bf16* __restrict__ whi,
                                            __bf16* __restrict__ wlo) {
  size_t i4 = ((size_t)blockIdx.x * 256 + threadIdx.x) * 4;
  float4 v = *(const float4*)&w[i4];
  float vv[4] = {v.x, v.y, v.z, v.w};
  bf16x4 h, l;
#pragma unroll
  for (int j = 0; j < 4; j++) {
    __bf16 hj = (__bf16)vv[j];
    float r = vv[j] - (float)hj;
    h[j] = hj;
    l[j] = (__bf16)r;
  }
  *(bf16x4*)&whi[i4] = h;
  *(bf16x4*)&wlo[i4] = l;
}

// ---------------- K1: sign GEMM, 3-term split-bf16 MFMA ----------------
// C[m,e] = x[m,:]·ag_w[e,:] + bias[e];  writes ST[b][e][hp] = (C>0 && hp<196) ? 1 : 0
// m = b*224 + hp (padded). Block tile 128x128, K-chunk 32, 4 waves 2x2 (64x64 each).
__global__ __launch_bounds__(256) void k1_signs(const __bf16* __restrict__ xhi,
                                                const __bf16* __restrict__ xlo,
                                                const __bf16* __restrict__ whi,
                                                const __bf16* __restrict__ wlo,
                                                const float* __restrict__ bias,
                                                __bf16* __restrict__ st) {
  __shared__ __bf16 Ah[128 * 40];  // +8 pad: banks spread, 2-way max (free per m136)
  __shared__ __bf16 Al[128 * 40];
  __shared__ __bf16 Bh[128 * 40];
  __shared__ __bf16 Bl[128 * 40];
  const int m0 = blockIdx.x * 128;
  const int n0 = blockIdx.y * 128;
  const int tid = threadIdx.x;
  const int wave = tid >> 6, lane = tid & 63;
  const int wm = (wave & 1) * 64, wn = (wave >> 1) * 64;
  const int q = lane >> 4, l15 = lane & 15;
  const int sr = tid >> 2;          // staging row 0..63 (two passes)
  const int sk = (tid & 3) * 8;     // staging k-offset
  f32x4 acc[4][4] = {};

  for (int k0 = 0; k0 < D_; k0 += 32) {
    __syncthreads();
#pragma unroll
    for (int rr = 0; rr < 128; rr += 64) {
      int r = sr + rr;
      *(bf16x8*)&Ah[r * 40 + sk] = *(const bf16x8*)&xhi[(size_t)(m0 + r) * D_ + k0 + sk];
      *(bf16x8*)&Al[r * 40 + sk] = *(const bf16x8*)&xlo[(size_t)(m0 + r) * D_ + k0 + sk];
      *(bf16x8*)&Bh[r * 40 + sk] = *(const bf16x8*)&whi[(size_t)(n0 + r) * D_ + k0 + sk];
      *(bf16x8*)&Bl[r * 40 + sk] = *(const bf16x8*)&wlo[(size_t)(n0 + r) * D_ + k0 + sk];
    }
    __syncthreads();
    bf16x8 af[4], alf[4], bfh[4], bfl[4];
#pragma unroll
    for (int t = 0; t < 4; t++) {
      af[t]  = *(const bf16x8*)&Ah[(wm + t * 16 + l15) * 40 + q * 8];
      alf[t] = *(const bf16x8*)&Al[(wm + t * 16 + l15) * 40 + q * 8];
      bfh[t] = *(const bf16x8*)&Bh[(wn + t * 16 + l15) * 40 + q * 8];
      bfl[t] = *(const bf16x8*)&Bl[(wn + t * 16 + l15) * 40 + q * 8];
    }
#pragma unroll
    for (int mt = 0; mt < 4; mt++)
#pragma unroll
      for (int nt = 0; nt < 4; nt++) {
        acc[mt][nt] = __builtin_amdgcn_mfma_f32_16x16x32_bf16(af[mt],  bfh[nt], acc[mt][nt], 0, 0, 0);
        acc[mt][nt] = __builtin_amdgcn_mfma_f32_16x16x32_bf16(alf[mt], bfh[nt], acc[mt][nt], 0, 0, 0);
        acc[mt][nt] = __builtin_amdgcn_mfma_f32_16x16x32_bf16(af[mt],  bfl[nt], acc[mt][nt], 0, 0, 0);
      }
  }
  // epilogue: +bias, sign, transposed store ST[b][e][hp] (pads hp>=196 get 0)
#pragma unroll
  for (int mt = 0; mt < 4; mt++)
#pragma unroll
    for (int nt = 0; nt < 4; nt++) {
      int e = n0 + wn + nt * 16 + l15;
      float bv = bias[e];
#pragma unroll
      for (int r = 0; r < 4; r++) {
        int m = m0 + wm + mt * 16 + q * 4 + r;   // C/D: row=quad*4+reg, col=lane&15 (m89/m91)
        int b = m / HWP_;
        int hp = m - b * HWP_;
        float v = acc[mt][nt][r] + bv;
        __bf16 s = (hp < HW_ && v > 0.0f) ? (__bf16)1.0f : (__bf16)0.0f;
        st[((size_t)b * E_ + e) * HWP_ + hp] = s;
      }
    }
}

// ---------------- K2: per-batch G = S^T · X  (M=256 e, N=768 d, K=224 hp) ----------------
__global__ __launch_bounds__(256) void k2_g(const __bf16* __restrict__ st,
                                            const __bf16* __restrict__ xhi,
                                            __bf16* __restrict__ g) {
  __shared__ __bf16 As[128 * 40];
  __shared__ __bf16 Bs[128 * 40];   // Bs[d][k] (transposed during staging)
  const int b  = blockIdx.y;
  const int e0 = (blockIdx.x / 6) * 128;
  const int d0 = (blockIdx.x % 6) * 128;
  const int tid = threadIdx.x;
  const int wave = tid >> 6, lane = tid & 63;
  const int wm = (wave & 1) * 64, wn = (wave >> 1) * 64;
  const int q = lane >> 4, l15 = lane & 15;
  const int sr = tid >> 2, sk = (tid & 3) * 8;     // A staging
  const int kk = tid >> 3, dc0 = (tid & 7) * 16;   // B staging (transpose)
  f32x4 acc[4][4] = {};

  for (int k0 = 0; k0 < HWP_; k0 += 32) {
    __syncthreads();
#pragma unroll
    for (int rr = 0; rr < 128; rr += 64) {
      int r = sr + rr;
      *(bf16x8*)&As[r * 40 + sk] =
          *(const bf16x8*)&st[((size_t)b * E_ + e0 + r) * HWP_ + k0 + sk];
    }
    {
      const __bf16* src = &xhi[((size_t)b * HWP_ + k0 + kk) * D_ + d0 + dc0];
      bf16x8 t0 = *(const bf16x8*)&src[0];
      bf16x8 t1 = *(const bf16x8*)&src[8];
#pragma unroll
      for (int j = 0; j < 8; j++) {
        Bs[(dc0 + j) * 40 + kk]     = t0[j];
        Bs[(dc0 + 8 + j) * 40 + kk] = t1[j];
      }
    }
    __syncthreads();
    bf16x8 af[4], bfr[4];
#pragma unroll
    for (int t = 0; t < 4; t++) {
      af[t]  = *(const bf16x8*)&As[(wm + t * 16 + l15) * 40 + q * 8];
      bfr[t] = *(const bf16x8*)&Bs[(wn + t * 16 + l15) * 40 + q * 8];
    }
#pragma unroll
    for (int mt = 0; mt < 4; mt++)
#pragma unroll
      for (int nt = 0; nt < 4; nt++)
        acc[mt][nt] = __builtin_amdgcn_mfma_f32_16x16x32_bf16(af[mt], bfr[nt], acc[mt][nt], 0, 0, 0);
  }
#pragma unroll
  for (int mt = 0; mt < 4; mt++)
#pragma unroll
    for (int nt = 0; nt < 4; nt++) {
      int d = d0 + wn + nt * 16 + l15;
#pragma unroll
      for (int r = 0; r < 4; r++) {
        int e = e0 + wm + mt * 16 + q * 4 + r;
        g[((size_t)b * E_ + e) * D_ + d] = (__bf16)acc[mt][nt][r];
      }
    }
}

// ---------------- K3: preds[b,c] += (1/(HW*E)) * Σ_d G[b,e,d] * lm_w[e*10+c, d] ----------------
__global__ __launch_bounds__(640) void k3_out(const __bf16* __restrict__ g,
                                              const float* __restrict__ lmw,
                                              float* __restrict__ out) {
  const int e = blockIdx.x;
  const int t = threadIdx.x;
  const int b = t / 10, c = t - b * 10;
  const __bf16* gr = &g[((size_t)b * E_ + e) * D_];
  const float* wr  = &lmw[(size_t)(e * C_ + c) * D_];
  float acc = 0.f;
  for (int d = 0; d < D_; d += 4) {
    bf16x4 gv = *(const bf16x4*)&gr[d];
    float4 wv = *(const float4*)&wr[d];
    acc += (float)gv[0] * wv.x + (float)gv[1] * wv.y + (float)gv[2] * wv.z + (float)gv[3] * wv.w;
  }
  atomicAdd(&out[b * C_ + c], acc * (1.0f / (196.0f * 256.0f)));
}

extern "C" void kernel_launch(void* const* d_in, const int* in_sizes, int n_in,
                              void* d_out, int out_size, void* d_ws, size_t ws_size,
                              hipStream_t stream) {
  const float* x    = (const float*)d_in[0];   // (64,196,768)
  const float* ag_w = (const float*)d_in[1];   // (256,768)
  const float* ag_b = (const float*)d_in[2];   // (256,)
  const float* lm_w = (const float*)d_in[3];   // (2560,768)
  float* out = (float*)d_out;                  // (64,10)

  char* ws = (char*)d_ws;
  const size_t XP_BYTES = (size_t)B_ * HWP_ * D_ * 2;   // 22,020,096
  const size_t W_BYTES  = (size_t)E_ * D_ * 2;          //    393,216
  const size_t ST_BYTES = (size_t)B_ * E_ * HWP_ * 2;   //  7,340,032
  __bf16* xhi = (__bf16*)(ws);
  __bf16* xlo = (__bf16*)(ws + XP_BYTES);
  __bf16* whi = (__bf16*)(ws + 2 * XP_BYTES);
  __bf16* wlo = (__bf16*)(ws + 2 * XP_BYTES + W_BYTES);
  __bf16* st  = (__bf16*)(ws + 2 * XP_BYTES + 2 * W_BYTES);
  __bf16* gb  = (__bf16*)(ws + 2 * XP_BYTES + 2 * W_BYTES + ST_BYTES);
  // total ws use: ~77.3 MB

  hipMemsetAsync(d_out, 0, (size_t)out_size * sizeof(float), stream);

  // K0: dtype prep
  k0_x<<<dim3((B_ * HWP_ * D_) / 4 / 256), dim3(256), 0, stream>>>(x, xhi, xlo);
  k0_w<<<dim3((E_ * D_) / 4 / 256), dim3(256), 0, stream>>>(ag_w, whi, wlo);
  // K1: sign GEMM (split-bf16 for fp32-grade sign boundaries)
  k1_signs<<<dim3(MP_ / 128, E_ / 128), dim3(256), 0, stream>>>(xhi, xlo, whi, wlo, ag_b, st);
  // K2: per-batch G = S^T X
  k2_g<<<dim3((E_ / 128) * (D_ / 128), B_), dim3(256), 0, stream>>>(st, xhi, gb);
  // K3: final contraction
  k3_out<<<dim3(E_), dim3(640), 0, stream>>>(gb, lm_w, out);
}

// Round 2
// 170.773 us; speedup vs baseline: 1.2827x; 1.2827x over previous
//
#include <hip/hip_runtime.h>

#define B_    64
#define HW_   196
#define HWP_  224
#define D_    768
#define E_    256
#define C_    10
#define MP_   (B_*HWP_)   // 14336 padded rows
#define K3K_  (E_*D_)     // 196608 deep-K for final contraction
#define K3NB_ 192         // K-split blocks for k3 (each: 1024 k, 4 waves x 256 k)

typedef __bf16 bf16x8 __attribute__((ext_vector_type(8)));
typedef __bf16 bf16x4 __attribute__((ext_vector_type(4)));
typedef float  f32x4  __attribute__((ext_vector_type(4)));

// ---------------- K0x: fp32 x -> bf16 hi/lo, zero-padded [B][HWP][D] ----------------
__global__ __launch_bounds__(256) void k0_x(const float* __restrict__ x,
                                            __bf16* __restrict__ xhi,
                                            __bf16* __restrict__ xlo) {
  size_t i4 = ((size_t)blockIdx.x * 256 + threadIdx.x) * 4;   // grid sized exactly
  int d  = (int)(i4 % D_);
  size_t row = i4 / D_;
  int hp = (int)(row % HWP_);
  int b  = (int)(row / HWP_);
  float4 v = make_float4(0.f, 0.f, 0.f, 0.f);
  if (hp < HW_) v = *(const float4*)&x[((size_t)b * HW_ + hp) * D_ + d];
  float vv[4] = {v.x, v.y, v.z, v.w};
  bf16x4 h, l;
#pragma unroll
  for (int j = 0; j < 4; j++) {
    __bf16 hj = (__bf16)vv[j];
    float r = vv[j] - (float)hj;
    h[j] = hj;
    l[j] = (__bf16)r;
  }
  *(bf16x4*)&xhi[i4] = h;
  *(bf16x4*)&xlo[i4] = l;
}

// ---------------- K0w: fp32 ag_w -> bf16 hi/lo [E][D] ----------------
__global__ __launch_bounds__(256) void k0_w(const float* __restrict__ w,
                                            __bf16* __restrict__ whi,
                                            __bf16* __restrict__ wlo) {
  size_t i4 = ((size_t)blockIdx.x * 256 + threadIdx.x) * 4;
  float4 v = *(const float4*)&w[i4];
  float vv[4] = {v.x, v.y, v.z, v.w};
  bf16x4 h, l;
#pragma unroll
  for (int j = 0; j < 4; j++) {
    __bf16 hj = (__bf16)vv[j];
    float r = vv[j] - (float)hj;
    h[j] = hj;
    l[j] = (__bf16)r;
  }
  *(bf16x4*)&whi[i4] = h;
  *(bf16x4*)&wlo[i4] = l;
}

// ---------------- K1: sign GEMM, 3-term split-bf16 MFMA ----------------
// C[m,e] = x[m,:]·ag_w[e,:] + bias[e];  writes ST[b][e][hp] = (C>0 && hp<196) ? 1 : 0
__global__ __launch_bounds__(256) void k1_signs(const __bf16* __restrict__ xhi,
                                                const __bf16* __restrict__ xlo,
                                                const __bf16* __restrict__ whi,
                                                const __bf16* __restrict__ wlo,
                                                const float* __restrict__ bias,
                                                __bf16* __restrict__ st) {
  __shared__ __bf16 Ah[128 * 40];
  __shared__ __bf16 Al[128 * 40];
  __shared__ __bf16 Bh[128 * 40];
  __shared__ __bf16 Bl[128 * 40];
  const int m0 = blockIdx.x * 128;
  const int n0 = blockIdx.y * 128;
  const int tid = threadIdx.x;
  const int wave = tid >> 6, lane = tid & 63;
  const int wm = (wave & 1) * 64, wn = (wave >> 1) * 64;
  const int q = lane >> 4, l15 = lane & 15;
  const int sr = tid >> 2;
  const int sk = (tid & 3) * 8;
  f32x4 acc[4][4] = {};

  for (int k0 = 0; k0 < D_; k0 += 32) {
    __syncthreads();
#pragma unroll
    for (int rr = 0; rr < 128; rr += 64) {
      int r = sr + rr;
      *(bf16x8*)&Ah[r * 40 + sk] = *(const bf16x8*)&xhi[(size_t)(m0 + r) * D_ + k0 + sk];
      *(bf16x8*)&Al[r * 40 + sk] = *(const bf16x8*)&xlo[(size_t)(m0 + r) * D_ + k0 + sk];
      *(bf16x8*)&Bh[r * 40 + sk] = *(const bf16x8*)&whi[(size_t)(n0 + r) * D_ + k0 + sk];
      *(bf16x8*)&Bl[r * 40 + sk] = *(const bf16x8*)&wlo[(size_t)(n0 + r) * D_ + k0 + sk];
    }
    __syncthreads();
    bf16x8 af[4], alf[4], bfh[4], bfl[4];
#pragma unroll
    for (int t = 0; t < 4; t++) {
      af[t]  = *(const bf16x8*)&Ah[(wm + t * 16 + l15) * 40 + q * 8];
      alf[t] = *(const bf16x8*)&Al[(wm + t * 16 + l15) * 40 + q * 8];
      bfh[t] = *(const bf16x8*)&Bh[(wn + t * 16 + l15) * 40 + q * 8];
      bfl[t] = *(const bf16x8*)&Bl[(wn + t * 16 + l15) * 40 + q * 8];
    }
#pragma unroll
    for (int mt = 0; mt < 4; mt++)
#pragma unroll
      for (int nt = 0; nt < 4; nt++) {
        acc[mt][nt] = __builtin_amdgcn_mfma_f32_16x16x32_bf16(af[mt],  bfh[nt], acc[mt][nt], 0, 0, 0);
        acc[mt][nt] = __builtin_amdgcn_mfma_f32_16x16x32_bf16(alf[mt], bfh[nt], acc[mt][nt], 0, 0, 0);
        acc[mt][nt] = __builtin_amdgcn_mfma_f32_16x16x32_bf16(af[mt],  bfl[nt], acc[mt][nt], 0, 0, 0);
      }
  }
#pragma unroll
  for (int mt = 0; mt < 4; mt++)
#pragma unroll
    for (int nt = 0; nt < 4; nt++) {
      int e = n0 + wn + nt * 16 + l15;
      float bv = bias[e];
#pragma unroll
      for (int r = 0; r < 4; r++) {
        int m = m0 + wm + mt * 16 + q * 4 + r;
        int b = m / HWP_;
        int hp = m - b * HWP_;
        float v = acc[mt][nt][r] + bv;
        __bf16 s = (hp < HW_ && v > 0.0f) ? (__bf16)1.0f : (__bf16)0.0f;
        st[((size_t)b * E_ + e) * HWP_ + hp] = s;
      }
    }
}

// ---------------- K2: per-batch G = S^T · X  (M=256 e, N=768 d, K=224 hp) ----------------
__global__ __launch_bounds__(256) void k2_g(const __bf16* __restrict__ st,
                                            const __bf16* __restrict__ xhi,
                                            __bf16* __restrict__ g) {
  __shared__ __bf16 As[128 * 40];
  __shared__ __bf16 Bs[128 * 40];   // Bs[d][k] (transposed during staging)
  const int b  = blockIdx.y;
  const int e0 = (blockIdx.x / 6) * 128;
  const int d0 = (blockIdx.x % 6) * 128;
  const int tid = threadIdx.x;
  const int wave = tid >> 6, lane = tid & 63;
  const int wm = (wave & 1) * 64, wn = (wave >> 1) * 64;
  const int q = lane >> 4, l15 = lane & 15;
  const int sr = tid >> 2, sk = (tid & 3) * 8;
  const int kk = tid >> 3, dc0 = (tid & 7) * 16;
  f32x4 acc[4][4] = {};

  for (int k0 = 0; k0 < HWP_; k0 += 32) {
    __syncthreads();
#pragma unroll
    for (int rr = 0; rr < 128; rr += 64) {
      int r = sr + rr;
      *(bf16x8*)&As[r * 40 + sk] =
          *(const bf16x8*)&st[((size_t)b * E_ + e0 + r) * HWP_ + k0 + sk];
    }
    {
      const __bf16* src = &xhi[((size_t)b * HWP_ + k0 + kk) * D_ + d0 + dc0];
      bf16x8 t0 = *(const bf16x8*)&src[0];
      bf16x8 t1 = *(const bf16x8*)&src[8];
#pragma unroll
      for (int j = 0; j < 8; j++) {
        Bs[(dc0 + j) * 40 + kk]     = t0[j];
        Bs[(dc0 + 8 + j) * 40 + kk] = t1[j];
      }
    }
    __syncthreads();
    bf16x8 af[4], bfr[4];
#pragma unroll
    for (int t = 0; t < 4; t++) {
      af[t]  = *(const bf16x8*)&As[(wm + t * 16 + l15) * 40 + q * 8];
      bfr[t] = *(const bf16x8*)&Bs[(wn + t * 16 + l15) * 40 + q * 8];
    }
#pragma unroll
    for (int mt = 0; mt < 4; mt++)
#pragma unroll
      for (int nt = 0; nt < 4; nt++)
        acc[mt][nt] = __builtin_amdgcn_mfma_f32_16x16x32_bf16(af[mt], bfr[nt], acc[mt][nt], 0, 0, 0);
  }
#pragma unroll
  for (int mt = 0; mt < 4; mt++)
#pragma unroll
    for (int nt = 0; nt < 4; nt++) {
      int d = d0 + wn + nt * 16 + l15;
#pragma unroll
      for (int r = 0; r < 4; r++) {
        int e = e0 + wm + mt * 16 + q * 4 + r;
        g[((size_t)b * E_ + e) * D_ + d] = (__bf16)acc[mt][nt][r];
      }
    }
}

// ---------------- K2b: permute lm_w -> W2[c][e*768+d] bf16, c padded to 16 ----------------
__global__ __launch_bounds__(192) void k2b_w2(const float* __restrict__ lmw,
                                              __bf16* __restrict__ w2) {
  const int e = blockIdx.x, c = blockIdx.y, t = threadIdx.x;
  __bf16* dst = &w2[(size_t)c * K3K_ + (size_t)e * D_ + t * 4];
  bf16x4 o;
  if (c < C_) {
    float4 v = *(const float4*)&lmw[((size_t)e * C_ + c) * D_ + t * 4];
    o[0] = (__bf16)v.x; o[1] = (__bf16)v.y; o[2] = (__bf16)v.z; o[3] = (__bf16)v.w;
  } else {
    o[0] = o[1] = o[2] = o[3] = (__bf16)0.0f;
  }
  *(bf16x4*)dst = o;
}

// ---------------- K3: preds = G_flat(64 x 196608) · W2^T, deep-K split MFMA ----------------
// Each block: K-chunk of 1024 (4 waves x 256). A = G rows (4 b-tiles of 16),
// B = W2 rows (16 c, 6 zero-pad). LDS-reduce 640 partials, one atomicAdd each.
__global__ __launch_bounds__(256) void k3_mfma(const __bf16* __restrict__ g,
                                               const __bf16* __restrict__ w2,
                                               float* __restrict__ out) {
  __shared__ float sp[B_ * C_];
  const int tid = threadIdx.x;
  const int wave = tid >> 6, lane = tid & 63;
  const int q = lane >> 4, l15 = lane & 15;
  const int kbase = blockIdx.x * (K3K_ / K3NB_) + wave * 256;
  f32x4 acc[4] = {};

  for (int i = tid; i < B_ * C_; i += 256) sp[i] = 0.0f;

#pragma unroll
  for (int ks = 0; ks < 8; ks++) {
    int k = kbase + ks * 32 + q * 8;
    bf16x8 bfrag = *(const bf16x8*)&w2[(size_t)l15 * K3K_ + k];
#pragma unroll
    for (int mt = 0; mt < 4; mt++) {
      bf16x8 afrag = *(const bf16x8*)&g[(size_t)(mt * 16 + l15) * K3K_ + k];
      acc[mt] = __builtin_amdgcn_mfma_f32_16x16x32_bf16(afrag, bfrag, acc[mt], 0, 0, 0);
    }
  }
  __syncthreads();
  int c = l15;
  if (c < C_) {
#pragma unroll
    for (int mt = 0; mt < 4; mt++)
#pragma unroll
      for (int r = 0; r < 4; r++) {
        int b = mt * 16 + q * 4 + r;
        atomicAdd(&sp[b * C_ + c], acc[mt][r]);
      }
  }
  __syncthreads();
  const float scale = 1.0f / (196.0f * 256.0f);
  for (int i = tid; i < B_ * C_; i += 256) atomicAdd(&out[i], sp[i] * scale);
}

extern "C" void kernel_launch(void* const* d_in, const int* in_sizes, int n_in,
                              void* d_out, int out_size, void* d_ws, size_t ws_size,
                              hipStream_t stream) {
  const float* x    = (const float*)d_in[0];   // (64,196,768)
  const float* ag_w = (const float*)d_in[1];   // (256,768)
  const float* ag_b = (const float*)d_in[2];   // (256,)
  const float* lm_w = (const float*)d_in[3];   // (2560,768)
  float* out = (float*)d_out;                  // (64,10)

  char* ws = (char*)d_ws;
  const size_t XP_BYTES = (size_t)B_ * HWP_ * D_ * 2;   // 22,020,096
  const size_t W_BYTES  = (size_t)E_ * D_ * 2;          //    393,216
  const size_t ST_BYTES = (size_t)B_ * E_ * HWP_ * 2;   //  7,340,032
  const size_t G_BYTES  = (size_t)B_ * E_ * D_ * 2;     // 25,165,824
  __bf16* xhi = (__bf16*)(ws);
  __bf16* xlo = (__bf16*)(ws + XP_BYTES);
  __bf16* whi = (__bf16*)(ws + 2 * XP_BYTES);
  __bf16* wlo = (__bf16*)(ws + 2 * XP_BYTES + W_BYTES);
  __bf16* st  = (__bf16*)(ws + 2 * XP_BYTES + 2 * W_BYTES);
  __bf16* gb  = (__bf16*)(ws + 2 * XP_BYTES + 2 * W_BYTES + ST_BYTES);
  __bf16* w2  = (__bf16*)(ws + 2 * XP_BYTES + 2 * W_BYTES + ST_BYTES + G_BYTES);
  // total ws use: ~84 MB (w2: 16*196608*2 = 6.3 MB)

  hipMemsetAsync(d_out, 0, (size_t)out_size * sizeof(float), stream);

  k0_x<<<dim3((B_ * HWP_ * D_) / 4 / 256), dim3(256), 0, stream>>>(x, xhi, xlo);
  k0_w<<<dim3((E_ * D_) / 4 / 256), dim3(256), 0, stream>>>(ag_w, whi, wlo);
  k2b_w2<<<dim3(E_, 16), dim3(192), 0, stream>>>(lm_w, w2);
  k1_signs<<<dim3(MP_ / 128, E_ / 128), dim3(256), 0, stream>>>(xhi, xlo, whi, wlo, ag_b, st);
  k2_g<<<dim3((E_ / 128) * (D_ / 128), B_), dim3(256), 0, stream>>>(st, xhi, gb);
  k3_mfma<<<dim3(K3NB_), dim3(256), 0, stream>>>(gb, w2, out);
}

// Round 3
// 169.824 us; speedup vs baseline: 1.2898x; 1.0056x over previous
//
#include <hip/hip_runtime.h>

#define B_    64
#define HW_   196
#define HWP_  224
#define D_    768
#define E_    256
#define C_    10
#define MP_   (B_*HWP_)   // 14336 padded rows
#define K3K_  (E_*D_)     // 196608 deep-K for final contraction
#define K3NB_ 192         // K-split blocks for k3

typedef __bf16 bf16x8 __attribute__((ext_vector_type(8)));
typedef __bf16 bf16x4 __attribute__((ext_vector_type(4)));
typedef float  f32x4  __attribute__((ext_vector_type(4)));

// ---------------- K0x: fp32 x -> bf16 hi/lo, zero-padded [B][HWP][D] ----------------
__global__ __launch_bounds__(256) void k0_x(const float* __restrict__ x,
                                            __bf16* __restrict__ xhi,
                                            __bf16* __restrict__ xlo) {
  size_t i4 = ((size_t)blockIdx.x * 256 + threadIdx.x) * 4;
  int d  = (int)(i4 % D_);
  size_t row = i4 / D_;
  int hp = (int)(row % HWP_);
  int b  = (int)(row / HWP_);
  float4 v = make_float4(0.f, 0.f, 0.f, 0.f);
  if (hp < HW_) v = *(const float4*)&x[((size_t)b * HW_ + hp) * D_ + d];
  float vv[4] = {v.x, v.y, v.z, v.w};
  bf16x4 h, l;
#pragma unroll
  for (int j = 0; j < 4; j++) {
    __bf16 hj = (__bf16)vv[j];
    float r = vv[j] - (float)hj;
    h[j] = hj;
    l[j] = (__bf16)r;
  }
  *(bf16x4*)&xhi[i4] = h;
  *(bf16x4*)&xlo[i4] = l;
}

// ---------------- K0w: fp32 ag_w -> bf16 hi/lo [E][D] ----------------
__global__ __launch_bounds__(256) void k0_w(const float* __restrict__ w,
                                            __bf16* __restrict__ whi,
                                            __bf16* __restrict__ wlo) {
  size_t i4 = ((size_t)blockIdx.x * 256 + threadIdx.x) * 4;
  float4 v = *(const float4*)&w[i4];
  float vv[4] = {v.x, v.y, v.z, v.w};
  bf16x4 h, l;
#pragma unroll
  for (int j = 0; j < 4; j++) {
    __bf16 hj = (__bf16)vv[j];
    float r = vv[j] - (float)hj;
    h[j] = hj;
    l[j] = (__bf16)r;
  }
  *(bf16x4*)&whi[i4] = h;
  *(bf16x4*)&wlo[i4] = l;
}

// ---------------- K1: sign GEMM, 3-term split-bf16 MFMA ----------------
// 64x64 tiles, 4 waves each 32x32 (2x2 frags) -> grid 224x4 = 896 blocks (~3.5/CU)
// vs R2's 128x128 / 224 blocks which capped occupancy at 1 block/CU (8% occ).
__global__ __launch_bounds__(256) void k1_signs(const __bf16* __restrict__ xhi,
                                                const __bf16* __restrict__ xlo,
                                                const __bf16* __restrict__ whi,
                                                const __bf16* __restrict__ wlo,
                                                const float* __restrict__ bias,
                                                __bf16* __restrict__ st) {
  __shared__ __bf16 Ah[64 * 40];   // stride 40: reads land 2-way (free), 16B-aligned rows
  __shared__ __bf16 Al[64 * 40];
  __shared__ __bf16 Bh[64 * 40];
  __shared__ __bf16 Bl[64 * 40];
  const int m0 = blockIdx.x * 64;
  const int n0 = blockIdx.y * 64;
  const int tid = threadIdx.x;
  const int wave = tid >> 6, lane = tid & 63;
  const int wm = (wave & 1) * 32, wn = (wave >> 1) * 32;
  const int q = lane >> 4, l15 = lane & 15;
  const int sr = tid >> 2;          // staging row 0..63
  const int sk = (tid & 3) * 8;     // staging k-offset (halves)
  f32x4 acc[2][2] = {};

  for (int k0 = 0; k0 < D_; k0 += 32) {
    __syncthreads();
    *(bf16x8*)&Ah[sr * 40 + sk] = *(const bf16x8*)&xhi[(size_t)(m0 + sr) * D_ + k0 + sk];
    *(bf16x8*)&Al[sr * 40 + sk] = *(const bf16x8*)&xlo[(size_t)(m0 + sr) * D_ + k0 + sk];
    *(bf16x8*)&Bh[sr * 40 + sk] = *(const bf16x8*)&whi[(size_t)(n0 + sr) * D_ + k0 + sk];
    *(bf16x8*)&Bl[sr * 40 + sk] = *(const bf16x8*)&wlo[(size_t)(n0 + sr) * D_ + k0 + sk];
    __syncthreads();
    bf16x8 af[2], alf[2], bfh[2], bfl[2];
#pragma unroll
    for (int t = 0; t < 2; t++) {
      af[t]  = *(const bf16x8*)&Ah[(wm + t * 16 + l15) * 40 + q * 8];
      alf[t] = *(const bf16x8*)&Al[(wm + t * 16 + l15) * 40 + q * 8];
      bfh[t] = *(const bf16x8*)&Bh[(wn + t * 16 + l15) * 40 + q * 8];
      bfl[t] = *(const bf16x8*)&Bl[(wn + t * 16 + l15) * 40 + q * 8];
    }
#pragma unroll
    for (int mt = 0; mt < 2; mt++)
#pragma unroll
      for (int nt = 0; nt < 2; nt++) {
        acc[mt][nt] = __builtin_amdgcn_mfma_f32_16x16x32_bf16(af[mt],  bfh[nt], acc[mt][nt], 0, 0, 0);
        acc[mt][nt] = __builtin_amdgcn_mfma_f32_16x16x32_bf16(alf[mt], bfh[nt], acc[mt][nt], 0, 0, 0);
        acc[mt][nt] = __builtin_amdgcn_mfma_f32_16x16x32_bf16(af[mt],  bfl[nt], acc[mt][nt], 0, 0, 0);
      }
  }
#pragma unroll
  for (int mt = 0; mt < 2; mt++)
#pragma unroll
    for (int nt = 0; nt < 2; nt++) {
      int e = n0 + wn + nt * 16 + l15;
      float bv = bias[e];
#pragma unroll
      for (int r = 0; r < 4; r++) {
        int m = m0 + wm + mt * 16 + q * 4 + r;   // C/D: row=quad*4+reg, col=lane&15
        int b = m / HWP_;
        int hp = m - b * HWP_;
        float v = acc[mt][nt][r] + bv;
        __bf16 s = (hp < HW_ && v > 0.0f) ? (__bf16)1.0f : (__bf16)0.0f;
        st[((size_t)b * E_ + e) * HWP_ + hp] = s;
      }
    }
}

// ---------------- K2: per-batch G = S^T · X  (M=256 e, N=768 d, K=224 hp) ----------------
__global__ __launch_bounds__(256) void k2_g(const __bf16* __restrict__ st,
                                            const __bf16* __restrict__ xhi,
                                            __bf16* __restrict__ g) {
  __shared__ __bf16 As[128 * 40];
  __shared__ __bf16 Bs[128 * 40];   // Bs[d][k] (transposed during staging)
  const int b  = blockIdx.y;
  const int e0 = (blockIdx.x / 6) * 128;
  const int d0 = (blockIdx.x % 6) * 128;
  const int tid = threadIdx.x;
  const int wave = tid >> 6, lane = tid & 63;
  const int wm = (wave & 1) * 64, wn = (wave >> 1) * 64;
  const int q = lane >> 4, l15 = lane & 15;
  const int sr = tid >> 2, sk = (tid & 3) * 8;
  const int kk = tid >> 3, dc0 = (tid & 7) * 16;
  f32x4 acc[4][4] = {};

  for (int k0 = 0; k0 < HWP_; k0 += 32) {
    __syncthreads();
#pragma unroll
    for (int rr = 0; rr < 128; rr += 64) {
      int r = sr + rr;
      *(bf16x8*)&As[r * 40 + sk] =
          *(const bf16x8*)&st[((size_t)b * E_ + e0 + r) * HWP_ + k0 + sk];
    }
    {
      const __bf16* src = &xhi[((size_t)b * HWP_ + k0 + kk) * D_ + d0 + dc0];
      bf16x8 t0 = *(const bf16x8*)&src[0];
      bf16x8 t1 = *(const bf16x8*)&src[8];
#pragma unroll
      for (int j = 0; j < 8; j++) {
        Bs[(dc0 + j) * 40 + kk]     = t0[j];
        Bs[(dc0 + 8 + j) * 40 + kk] = t1[j];
      }
    }
    __syncthreads();
    bf16x8 af[4], bfr[4];
#pragma unroll
    for (int t = 0; t < 4; t++) {
      af[t]  = *(const bf16x8*)&As[(wm + t * 16 + l15) * 40 + q * 8];
      bfr[t] = *(const bf16x8*)&Bs[(wn + t * 16 + l15) * 40 + q * 8];
    }
#pragma unroll
    for (int mt = 0; mt < 4; mt++)
#pragma unroll
      for (int nt = 0; nt < 4; nt++)
        acc[mt][nt] = __builtin_amdgcn_mfma_f32_16x16x32_bf16(af[mt], bfr[nt], acc[mt][nt], 0, 0, 0);
  }
#pragma unroll
  for (int mt = 0; mt < 4; mt++)
#pragma unroll
    for (int nt = 0; nt < 4; nt++) {
      int d = d0 + wn + nt * 16 + l15;
#pragma unroll
      for (int r = 0; r < 4; r++) {
        int e = e0 + wm + mt * 16 + q * 4 + r;
        g[((size_t)b * E_ + e) * D_ + d] = (__bf16)acc[mt][nt][r];
      }
    }
}

// ---------------- K2b: permute lm_w -> W2[c][e*768+d] bf16, c padded to 16 ----------------
__global__ __launch_bounds__(192) void k2b_w2(const float* __restrict__ lmw,
                                              __bf16* __restrict__ w2) {
  const int e = blockIdx.x, c = blockIdx.y, t = threadIdx.x;
  __bf16* dst = &w2[(size_t)c * K3K_ + (size_t)e * D_ + t * 4];
  bf16x4 o;
  if (c < C_) {
    float4 v = *(const float4*)&lmw[((size_t)e * C_ + c) * D_ + t * 4];
    o[0] = (__bf16)v.x; o[1] = (__bf16)v.y; o[2] = (__bf16)v.z; o[3] = (__bf16)v.w;
  } else {
    o[0] = o[1] = o[2] = o[3] = (__bf16)0.0f;
  }
  *(bf16x4*)dst = o;
}

// ---------------- K3: preds = G_flat(64 x 196608) · W2^T, deep-K split MFMA ----------------
__global__ __launch_bounds__(256) void k3_mfma(const __bf16* __restrict__ g,
                                               const __bf16* __restrict__ w2,
                                               float* __restrict__ out) {
  __shared__ float sp[B_ * C_];
  const int tid = threadIdx.x;
  const int wave = tid >> 6, lane = tid & 63;
  const int q = lane >> 4, l15 = lane & 15;
  const int kbase = blockIdx.x * (K3K_ / K3NB_) + wave * 256;
  f32x4 acc[4] = {};

  for (int i = tid; i < B_ * C_; i += 256) sp[i] = 0.0f;

#pragma unroll
  for (int ks = 0; ks < 8; ks++) {
    int k = kbase + ks * 32 + q * 8;
    bf16x8 bfrag = *(const bf16x8*)&w2[(size_t)l15 * K3K_ + k];
#pragma unroll
    for (int mt = 0; mt < 4; mt++) {
      bf16x8 afrag = *(const bf16x8*)&g[(size_t)(mt * 16 + l15) * K3K_ + k];
      acc[mt] = __builtin_amdgcn_mfma_f32_16x16x32_bf16(afrag, bfrag, acc[mt], 0, 0, 0);
    }
  }
  __syncthreads();
  int c = l15;
  if (c < C_) {
#pragma unroll
    for (int mt = 0; mt < 4; mt++)
#pragma unroll
      for (int r = 0; r < 4; r++) {
        int b = mt * 16 + q * 4 + r;
        atomicAdd(&sp[b * C_ + c], acc[mt][r]);
      }
  }
  __syncthreads();
  const float scale = 1.0f / (196.0f * 256.0f);
  for (int i = tid; i < B_ * C_; i += 256) atomicAdd(&out[i], sp[i] * scale);
}

extern "C" void kernel_launch(void* const* d_in, const int* in_sizes, int n_in,
                              void* d_out, int out_size, void* d_ws, size_t ws_size,
                              hipStream_t stream) {
  const float* x    = (const float*)d_in[0];   // (64,196,768)
  const float* ag_w = (const float*)d_in[1];   // (256,768)
  const float* ag_b = (const float*)d_in[2];   // (256,)
  const float* lm_w = (const float*)d_in[3];   // (2560,768)
  float* out = (float*)d_out;                  // (64,10)

  char* ws = (char*)d_ws;
  const size_t XP_BYTES = (size_t)B_ * HWP_ * D_ * 2;
  const size_t W_BYTES  = (size_t)E_ * D_ * 2;
  const size_t ST_BYTES = (size_t)B_ * E_ * HWP_ * 2;
  const size_t G_BYTES  = (size_t)B_ * E_ * D_ * 2;
  __bf16* xhi = (__bf16*)(ws);
  __bf16* xlo = (__bf16*)(ws + XP_BYTES);
  __bf16* whi = (__bf16*)(ws + 2 * XP_BYTES);
  __bf16* wlo = (__bf16*)(ws + 2 * XP_BYTES + W_BYTES);
  __bf16* st  = (__bf16*)(ws + 2 * XP_BYTES + 2 * W_BYTES);
  __bf16* gb  = (__bf16*)(ws + 2 * XP_BYTES + 2 * W_BYTES + ST_BYTES);
  __bf16* w2  = (__bf16*)(ws + 2 * XP_BYTES + 2 * W_BYTES + ST_BYTES + G_BYTES);

  hipMemsetAsync(d_out, 0, (size_t)out_size * sizeof(float), stream);

  k0_x<<<dim3((B_ * HWP_ * D_) / 4 / 256), dim3(256), 0, stream>>>(x, xhi, xlo);
  k0_w<<<dim3((E_ * D_) / 4 / 256), dim3(256), 0, stream>>>(ag_w, whi, wlo);
  k2b_w2<<<dim3(E_, 16), dim3(192), 0, stream>>>(lm_w, w2);
  k1_signs<<<dim3(MP_ / 64, E_ / 64), dim3(256), 0, stream>>>(xhi, xlo, whi, wlo, ag_b, st);
  k2_g<<<dim3((E_ / 128) * (D_ / 128), B_), dim3(256), 0, stream>>>(st, xhi, gb);
  k3_mfma<<<dim3(K3NB_), dim3(256), 0, stream>>>(gb, w2, out);
}